// Round 2
// baseline (432.622 us; speedup 1.0000x reference)
//
#include <hip/hip_runtime.h>
#include <math.h>

namespace {
constexpr int B_ = 8;
constexpr int D_ = 256;
constexpr int H_ = 56;
constexpr int W_ = 56;
constexpr int HW_ = H_ * W_;   // 3136
constexpr int M_ = B_ * HW_;   // 25088
}

// ---------------- K1: depthwise 3x3 qk conv -> q,k in (b,p,c) layout --------
// conv output channel oc (0..511) uses input channel oc>>1 (XLA group rule).
// oc<256 -> q channel oc ; oc>=256 -> k channel oc-256.
__global__ __launch_bounds__(64) void k_qkconv(
        const float* __restrict__ x, const float* __restrict__ qkw,
        const float* __restrict__ qkb,
        float* __restrict__ q, float* __restrict__ k) {
    const int bid = blockIdx.x;
    const int g = bid & 7;                 // 8 groups of 64 out-channels
    const int y = (bid >> 3) % H_;
    const int b = bid / (8 * H_);
    const int tid = threadIdx.x;           // 0..63
    const int oc = g * 64 + tid;           // 0..511
    const int cin0 = g * 32;
    __shared__ float xs[32][3][58];
    for (int lin = tid; lin < 32 * 3 * 58; lin += 64) {
        const int ci = lin / 174;
        const int r = (lin / 58) % 3;
        const int col = lin % 58;
        const int yy = y - 1 + r;
        const int xx = col - 1;
        float v = 0.f;
        if ((unsigned)yy < (unsigned)H_ && (unsigned)xx < (unsigned)W_)
            v = x[((b * D_ + cin0 + ci) * H_ + yy) * W_ + xx];
        xs[ci][r][col] = v;
    }
    __syncthreads();
    float w[9];
#pragma unroll
    for (int t = 0; t < 9; ++t) w[t] = qkw[oc * 9 + t];
    const float bias = qkb[oc];
    const int cl = tid >> 1;               // local cin
    float* const dst = (oc < 256) ? q : k;
    const int od = oc & 255;
    for (int xx = 0; xx < W_; ++xx) {
        float acc = bias;
#pragma unroll
        for (int t = 0; t < 9; ++t)
            acc = fmaf(w[t], xs[cl][t / 3][xx + (t % 3)], acc);
        dst[(b * HW_ + y * W_ + xx) * D_ + od] = acc;
    }
}

// ---------------- K2: v = 1x1 conv, out layout (b,p,c) ----------------------
// GEMM: vv[m][o] = sum_c x[b(m)][c][p(m)] * vw[o][c] + vb[o]
__global__ __launch_bounds__(256) void k_vgemm(
        const float* __restrict__ x, const float* __restrict__ vw,
        const float* __restrict__ vb, float* __restrict__ vv) {
    const int m0 = blockIdx.x * 128;
    const int o0 = blockIdx.y * 64;
    const int tid = threadIdx.x;
    const int tp = tid & 15;
    const int to = tid >> 4;               // 0..15
    __shared__ float A_sh[16][132];
    __shared__ float W_sh[16][68];
    float acc[8][4] = {};
    for (int c0 = 0; c0 < D_; c0 += 16) {
        float4 a[2];
#pragma unroll
        for (int r = 0; r < 2; ++r) {
            const int lin4 = tid + r * 256;
            const int c_l = lin4 >> 5;
            const int m_l = (lin4 & 31) * 4;
            const int m = m0 + m_l;
            const int bb = m / HW_;
            const int p = m - bb * HW_;
            a[r] = *(const float4*)&x[(bb * D_ + c0 + c_l) * HW_ + p];
        }
        const int o_l = tid >> 2;
        const int c_l4 = (tid & 3) * 4;
        const float4 wv = *(const float4*)&vw[(o0 + o_l) * D_ + c0 + c_l4];
        __syncthreads();
#pragma unroll
        for (int r = 0; r < 2; ++r) {
            const int lin4 = tid + r * 256;
            const int c_l = lin4 >> 5;
            const int m_l = (lin4 & 31) * 4;
            *(float4*)&A_sh[c_l][m_l] = a[r];
        }
        W_sh[c_l4 + 0][o_l] = wv.x;
        W_sh[c_l4 + 1][o_l] = wv.y;
        W_sh[c_l4 + 2][o_l] = wv.z;
        W_sh[c_l4 + 3][o_l] = wv.w;
        __syncthreads();
#pragma unroll
        for (int kk = 0; kk < 16; ++kk) {
            const float4 a0 = *(const float4*)&A_sh[kk][tp * 4];
            const float4 a1 = *(const float4*)&A_sh[kk][64 + tp * 4];
            const float4 w4 = *(const float4*)&W_sh[kk][to * 4];
            const float am[8] = {a0.x, a0.y, a0.z, a0.w, a1.x, a1.y, a1.z, a1.w};
            const float wm[4] = {w4.x, w4.y, w4.z, w4.w};
#pragma unroll
            for (int i = 0; i < 8; ++i)
#pragma unroll
                for (int j = 0; j < 4; ++j)
                    acc[i][j] = fmaf(am[i], wm[j], acc[i][j]);
        }
    }
    const float4 vb4 = *(const float4*)&vb[o0 + to * 4];
    const float bv[4] = {vb4.x, vb4.y, vb4.z, vb4.w};
#pragma unroll
    for (int i = 0; i < 8; ++i) {
        const int m_l = (i < 4) ? (tp * 4 + i) : (64 + tp * 4 + i - 4);
        const int m = m0 + m_l;
        float4 o4;
        o4.x = acc[i][0] + bv[0];
        o4.y = acc[i][1] + bv[1];
        o4.z = acc[i][2] + bv[2];
        o4.w = acc[i][3] + bv[3];
        *(float4*)&vv[m * D_ + o0 + to * 4] = o4;
    }
}

// ---------------- K3: per-pixel 32x32 channel attention ---------------------
// One wave per p2. u[c][t], t=kp*HW+p is the unfold plane; needed t = p2*9+k2.
__global__ __launch_bounds__(256) void k_attn(
        const float* __restrict__ q, const float* __restrict__ kko,
        const float* __restrict__ v, float* __restrict__ qkv) {
    const int wid = threadIdx.x >> 6;
    const int lane = threadIdx.x & 63;
    const int p2 = blockIdx.x * 4 + wid;
    const int bh = blockIdx.y;
    const int b = bh >> 3;
    const int cbase = (bh & 7) * 32;
    __shared__ float uq[4][9][32];
    __shared__ float uk[4][9][32];
    __shared__ float vs[4][32];
    const int cl = lane & 31;
    const float* const src = (lane < 32) ? q : kko;
#pragma unroll
    for (int k2 = 0; k2 < 9; ++k2) {
        const int t = p2 * 9 + k2;
        const int kp = t / HW_;            // kernel position 0..8
        const int pp = t - kp * HW_;       // spatial index
        const int yy = pp / W_;
        const int xx = pp - yy * W_;
        const int sy = yy + kp / 3 - 1;
        const int sx = xx + kp % 3 - 1;
        float val = 0.f;
        if ((unsigned)sy < (unsigned)H_ && (unsigned)sx < (unsigned)W_)
            val = src[(b * HW_ + sy * W_ + sx) * D_ + cbase + cl];
        if (lane < 32) uq[wid][k2][cl] = val;
        else           uk[wid][k2][cl] = val;
    }
    if (lane < 32) vs[wid][cl] = v[(b * HW_ + p2) * D_ + cbase + cl];
    __syncthreads();
    const int ti = lane >> 3;              // row group (4 rows)
    const int tj = lane & 7;               // col group (4 cols)
    float acc[4][4] = {};
#pragma unroll
    for (int k2 = 0; k2 < 9; ++k2) {
        const float4 a4 = *(const float4*)&uq[wid][k2][ti * 4];
        const float4 b4 = *(const float4*)&uk[wid][k2][tj * 4];
        const float av[4] = {a4.x, a4.y, a4.z, a4.w};
        const float bw[4] = {b4.x, b4.y, b4.z, b4.w};
#pragma unroll
        for (int i = 0; i < 4; ++i)
#pragma unroll
            for (int j = 0; j < 4; ++j)
                acc[i][j] = fmaf(av[i], bw[j], acc[i][j]);
    }
    const float4 v4 = *(const float4*)&vs[wid][tj * 4];
    const float vvv[4] = {v4.x, v4.y, v4.z, v4.w};
    float outv[4];
#pragma unroll
    for (int i = 0; i < 4; ++i) {
        float mx = fmaxf(fmaxf(acc[i][0], acc[i][1]), fmaxf(acc[i][2], acc[i][3]));
        mx = fmaxf(mx, __shfl_xor(mx, 1));
        mx = fmaxf(mx, __shfl_xor(mx, 2));
        mx = fmaxf(mx, __shfl_xor(mx, 4));
        float s = 0.f, pv = 0.f;
#pragma unroll
        for (int j = 0; j < 4; ++j) {
            const float e = __expf(acc[i][j] - mx);
            s += e;
            pv = fmaf(e, vvv[j], pv);
        }
        s += __shfl_xor(s, 1);  s += __shfl_xor(s, 2);  s += __shfl_xor(s, 4);
        pv += __shfl_xor(pv, 1); pv += __shfl_xor(pv, 2); pv += __shfl_xor(pv, 4);
        outv[i] = pv / s;
    }
    if (tj == 0) {
        float4 o4 = {outv[0], outv[1], outv[2], outv[3]};
        *(float4*)&qkv[(b * HW_ + p2) * D_ + cbase + ti * 4] = o4;
    }
}

// ---------------- K4: proj 1x1 + BN + SiLU + residual, out (b,c,p) ----------
__global__ __launch_bounds__(256) void k_proj(
        const float* __restrict__ qkv, const float* __restrict__ pw,
        const float* __restrict__ pb, const float* __restrict__ gamma,
        const float* __restrict__ beta, const float* __restrict__ mean,
        const float* __restrict__ var, const float* __restrict__ x,
        float* __restrict__ out) {
    const int m0 = blockIdx.x * 128;
    const int o0 = blockIdx.y * 64;
    const int tid = threadIdx.x;
    const int tp = tid & 15;
    const int to = tid >> 4;
    __shared__ float Q_sh[16][132];
    __shared__ float W_sh[16][68];
    float acc[8][4] = {};
    for (int c0 = 0; c0 < D_; c0 += 16) {
        float4 a[2];
#pragma unroll
        for (int r = 0; r < 2; ++r) {
            const int lin4 = tid + r * 256;
            const int m_l = lin4 >> 2;
            const int c_l4 = (lin4 & 3) * 4;
            a[r] = *(const float4*)&qkv[(m0 + m_l) * D_ + c0 + c_l4];
        }
        const int o_l = tid >> 2;
        const int c_l4w = (tid & 3) * 4;
        const float4 wv = *(const float4*)&pw[(o0 + o_l) * D_ + c0 + c_l4w];
        __syncthreads();
#pragma unroll
        for (int r = 0; r < 2; ++r) {
            const int lin4 = tid + r * 256;
            const int m_l = lin4 >> 2;
            const int c_l4 = (lin4 & 3) * 4;
            Q_sh[c_l4 + 0][m_l] = a[r].x;
            Q_sh[c_l4 + 1][m_l] = a[r].y;
            Q_sh[c_l4 + 2][m_l] = a[r].z;
            Q_sh[c_l4 + 3][m_l] = a[r].w;
        }
        W_sh[c_l4w + 0][o_l] = wv.x;
        W_sh[c_l4w + 1][o_l] = wv.y;
        W_sh[c_l4w + 2][o_l] = wv.z;
        W_sh[c_l4w + 3][o_l] = wv.w;
        __syncthreads();
#pragma unroll
        for (int kk = 0; kk < 16; ++kk) {
            const float4 a0 = *(const float4*)&Q_sh[kk][tp * 4];
            const float4 a1 = *(const float4*)&Q_sh[kk][64 + tp * 4];
            const float4 w4 = *(const float4*)&W_sh[kk][to * 4];
            const float am[8] = {a0.x, a0.y, a0.z, a0.w, a1.x, a1.y, a1.z, a1.w};
            const float wm[4] = {w4.x, w4.y, w4.z, w4.w};
#pragma unroll
            for (int i = 0; i < 8; ++i)
#pragma unroll
                for (int j = 0; j < 4; ++j)
                    acc[i][j] = fmaf(am[i], wm[j], acc[i][j]);
        }
    }
    const int ob = o0 + to * 4;
    const float4 pb4 = *(const float4*)&pb[ob];
    const float4 gm4 = *(const float4*)&gamma[ob];
    const float4 bt4 = *(const float4*)&beta[ob];
    const float4 mn4 = *(const float4*)&mean[ob];
    const float4 vr4 = *(const float4*)&var[ob];
    const float pbv[4] = {pb4.x, pb4.y, pb4.z, pb4.w};
    const float mnv[4] = {mn4.x, mn4.y, mn4.z, mn4.w};
    const float btv[4] = {bt4.x, bt4.y, bt4.z, bt4.w};
    const float gmv[4] = {gm4.x, gm4.y, gm4.z, gm4.w};
    const float vrv[4] = {vr4.x, vr4.y, vr4.z, vr4.w};
    float invv[4];
#pragma unroll
    for (int j = 0; j < 4; ++j) invv[j] = gmv[j] * rsqrtf(vrv[j] + 1e-5f);
#pragma unroll
    for (int j = 0; j < 4; ++j) {
        const int oG = ob + j;
#pragma unroll
        for (int half = 0; half < 2; ++half) {
            const int m = m0 + half * 64 + tp * 4;   // 4 consecutive m, same b
            const int bb = m / HW_;
            const int p = m - bb * HW_;
            const int base = (bb * D_ + oG) * HW_ + p;
            const float4 ide = *(const float4*)&x[base];
            const float idev[4] = {ide.x, ide.y, ide.z, ide.w};
            float rr[4];
#pragma unroll
            for (int i = 0; i < 4; ++i) {
                const float val = acc[half * 4 + i][j] + pbv[j];
                const float xn = (val - mnv[j]) * invv[j] + btv[j];
                const float sg = 1.f / (1.f + __expf(-xn));
                rr[i] = xn * sg + idev[i];
            }
            float4 r4 = {rr[0], rr[1], rr[2], rr[3]};
            *(float4*)&out[base] = r4;
        }
    }
}

extern "C" void kernel_launch(void* const* d_in, const int* in_sizes, int n_in,
                              void* d_out, int out_size, void* d_ws, size_t ws_size,
                              hipStream_t stream) {
    const float* x   = (const float*)d_in[0];
    const float* qkw = (const float*)d_in[1];
    const float* qkb = (const float*)d_in[2];
    const float* vw  = (const float*)d_in[3];
    const float* vb  = (const float*)d_in[4];
    const float* pw  = (const float*)d_in[5];
    const float* pb  = (const float*)d_in[6];
    const float* gm  = (const float*)d_in[7];
    const float* bt  = (const float*)d_in[8];
    const float* mn  = (const float*)d_in[9];
    const float* vr  = (const float*)d_in[10];
    float* out = (float*)d_out;

    float* q   = (float*)d_ws;                    // (b,p,c) 25.7 MB
    float* kk  = q + (size_t)M_ * D_;             // (b,p,c)
    float* vv  = kk + (size_t)M_ * D_;            // (b,p,c)
    float* qkv = vv + (size_t)M_ * D_;            // (b,p,c)

    k_qkconv<<<dim3(8 * H_ * B_), dim3(64), 0, stream>>>(x, qkw, qkb, q, kk);
    k_vgemm<<<dim3(M_ / 128, 4), dim3(256), 0, stream>>>(x, vw, vb, vv);
    k_attn<<<dim3(HW_ / 4, 64), dim3(256), 0, stream>>>(q, kk, vv, qkv);
    k_proj<<<dim3(M_ / 128, 4), dim3(256), 0, stream>>>(qkv, pw, pb, gm, bt, mn, vr, x, out);
}

// Round 3
// 394.088 us; speedup vs baseline: 1.0978x; 1.0978x over previous
//
#include <hip/hip_runtime.h>
#include <math.h>

namespace {
constexpr int B_ = 8;
constexpr int D_ = 256;
constexpr int H_ = 56;
constexpr int W_ = 56;
constexpr int HW_ = H_ * W_;   // 3136
constexpr int M_ = B_ * HW_;   // 25088
}

// ---------------- K1: depthwise 3x3 qk conv -> q,k in (b,p,c) layout --------
// conv output channel oc (0..511) uses input channel oc>>1 (XLA group rule).
// oc<256 -> q channel oc ; oc>=256 -> k channel oc-256.
__global__ __launch_bounds__(64) void k_qkconv(
        const float* __restrict__ x, const float* __restrict__ qkw,
        const float* __restrict__ qkb,
        float* __restrict__ q, float* __restrict__ k) {
    const int bid = blockIdx.x;
    const int g = bid & 7;                 // 8 groups of 64 out-channels
    const int y = (bid >> 3) % H_;
    const int b = bid / (8 * H_);
    const int tid = threadIdx.x;           // 0..63
    const int oc = g * 64 + tid;           // 0..511
    const int cin0 = g * 32;
    __shared__ float xs[32][3][58];
    for (int lin = tid; lin < 32 * 3 * 58; lin += 64) {
        const int ci = lin / 174;
        const int r = (lin / 58) % 3;
        const int col = lin % 58;
        const int yy = y - 1 + r;
        const int xx = col - 1;
        float v = 0.f;
        if ((unsigned)yy < (unsigned)H_ && (unsigned)xx < (unsigned)W_)
            v = x[((b * D_ + cin0 + ci) * H_ + yy) * W_ + xx];
        xs[ci][r][col] = v;
    }
    __syncthreads();
    float w[9];
#pragma unroll
    for (int t = 0; t < 9; ++t) w[t] = qkw[oc * 9 + t];
    const float bias = qkb[oc];
    const int cl = tid >> 1;               // local cin
    float* const dst = (oc < 256) ? q : k;
    const int od = oc & 255;
    for (int xx = 0; xx < W_; ++xx) {
        float acc = bias;
#pragma unroll
        for (int t = 0; t < 9; ++t)
            acc = fmaf(w[t], xs[cl][t / 3][xx + (t % 3)], acc);
        dst[(b * HW_ + y * W_ + xx) * D_ + od] = acc;
    }
}

// ---------------- K2: v = 1x1 conv, out layout (b,p,c) ----------------------
// GEMM: vv[m][o] = sum_c x[b(m)][c][p(m)] * vw[o][c] + vb[o]
__global__ __launch_bounds__(256) void k_vgemm(
        const float* __restrict__ x, const float* __restrict__ vw,
        const float* __restrict__ vb, float* __restrict__ vv) {
    const int m0 = blockIdx.x * 128;
    const int o0 = blockIdx.y * 64;
    const int tid = threadIdx.x;
    const int tp = tid & 15;
    const int to = tid >> 4;               // 0..15
    __shared__ float A_sh[16][132];
    __shared__ float W_sh[16][68];
    float acc[8][4] = {};
    for (int c0 = 0; c0 < D_; c0 += 16) {
        float4 a[2];
#pragma unroll
        for (int r = 0; r < 2; ++r) {
            const int lin4 = tid + r * 256;
            const int c_l = lin4 >> 5;
            const int m_l = (lin4 & 31) * 4;
            const int m = m0 + m_l;
            const int bb = m / HW_;
            const int p = m - bb * HW_;
            a[r] = *(const float4*)&x[(bb * D_ + c0 + c_l) * HW_ + p];
        }
        const int o_l = tid >> 2;
        const int c_l4 = (tid & 3) * 4;
        const float4 wv = *(const float4*)&vw[(o0 + o_l) * D_ + c0 + c_l4];
        __syncthreads();
#pragma unroll
        for (int r = 0; r < 2; ++r) {
            const int lin4 = tid + r * 256;
            const int c_l = lin4 >> 5;
            const int m_l = (lin4 & 31) * 4;
            *(float4*)&A_sh[c_l][m_l] = a[r];
        }
        W_sh[c_l4 + 0][o_l] = wv.x;
        W_sh[c_l4 + 1][o_l] = wv.y;
        W_sh[c_l4 + 2][o_l] = wv.z;
        W_sh[c_l4 + 3][o_l] = wv.w;
        __syncthreads();
#pragma unroll
        for (int kk = 0; kk < 16; ++kk) {
            const float4 a0 = *(const float4*)&A_sh[kk][tp * 4];
            const float4 a1 = *(const float4*)&A_sh[kk][64 + tp * 4];
            const float4 w4 = *(const float4*)&W_sh[kk][to * 4];
            const float am[8] = {a0.x, a0.y, a0.z, a0.w, a1.x, a1.y, a1.z, a1.w};
            const float wm[4] = {w4.x, w4.y, w4.z, w4.w};
#pragma unroll
            for (int i = 0; i < 8; ++i)
#pragma unroll
                for (int j = 0; j < 4; ++j)
                    acc[i][j] = fmaf(am[i], wm[j], acc[i][j]);
        }
    }
    const float4 vb4 = *(const float4*)&vb[o0 + to * 4];
    const float bv[4] = {vb4.x, vb4.y, vb4.z, vb4.w};
#pragma unroll
    for (int i = 0; i < 8; ++i) {
        const int m_l = (i < 4) ? (tp * 4 + i) : (64 + tp * 4 + i - 4);
        const int m = m0 + m_l;
        float4 o4;
        o4.x = acc[i][0] + bv[0];
        o4.y = acc[i][1] + bv[1];
        o4.z = acc[i][2] + bv[2];
        o4.w = acc[i][3] + bv[3];
        *(float4*)&vv[m * D_ + o0 + to * 4] = o4;
    }
}

// ---------------- K3: per-pixel 32x32 channel attention ---------------------
// One block per (b, p2), all 8 heads. Stage 9 q-rows + 9 k-rows + v-row
// (256 ch each) in LDS once; 4 waves x 2 heads compute 32x32 attention.
__global__ __launch_bounds__(256) void k_attn(
        const float* __restrict__ q, const float* __restrict__ kko,
        const float* __restrict__ v, float* __restrict__ qkv) {
    const int p2 = blockIdx.x;
    const int b = blockIdx.y;
    const int tid = threadIdx.x;
    __shared__ float qs[9][256];
    __shared__ float ks[9][256];
    __shared__ float vs[256];
    const size_t rowbase = (size_t)(b * HW_) * D_;
#pragma unroll
    for (int k2 = 0; k2 < 9; ++k2) {
        const int t = p2 * 9 + k2;
        const int kp = t / HW_;            // kernel position 0..8
        const int pp = t - kp * HW_;       // spatial index in plane
        const int yy = pp / W_;
        const int xx = pp - yy * W_;
        const int sy = yy + kp / 3 - 1;
        const int sx = xx + kp % 3 - 1;
        float qv = 0.f, kv = 0.f;
        if ((unsigned)sy < (unsigned)H_ && (unsigned)sx < (unsigned)W_) {
            const size_t off = rowbase + (size_t)(sy * W_ + sx) * D_ + tid;
            qv = q[off];
            kv = kko[off];
        }
        qs[k2][tid] = qv;
        ks[k2][tid] = kv;
    }
    vs[tid] = v[rowbase + (size_t)p2 * D_ + tid];
    __syncthreads();
    const int wid = tid >> 6;
    const int lane = tid & 63;
    const int ti = lane >> 3;              // row group (4 rows)
    const int tj = lane & 7;               // col group (4 cols)
#pragma unroll
    for (int hh = 0; hh < 2; ++hh) {
        const int cbase = (wid + hh * 4) * 32;
        float acc[4][4] = {};
#pragma unroll
        for (int k2 = 0; k2 < 9; ++k2) {
            const float4 a4 = *(const float4*)&qs[k2][cbase + ti * 4];
            const float4 b4 = *(const float4*)&ks[k2][cbase + tj * 4];
            const float av[4] = {a4.x, a4.y, a4.z, a4.w};
            const float bw[4] = {b4.x, b4.y, b4.z, b4.w};
#pragma unroll
            for (int i = 0; i < 4; ++i)
#pragma unroll
                for (int j = 0; j < 4; ++j)
                    acc[i][j] = fmaf(av[i], bw[j], acc[i][j]);
        }
        const float4 v4 = *(const float4*)&vs[cbase + tj * 4];
        const float vvv[4] = {v4.x, v4.y, v4.z, v4.w};
        float outv[4];
#pragma unroll
        for (int i = 0; i < 4; ++i) {
            float mx = fmaxf(fmaxf(acc[i][0], acc[i][1]), fmaxf(acc[i][2], acc[i][3]));
            mx = fmaxf(mx, __shfl_xor(mx, 1));
            mx = fmaxf(mx, __shfl_xor(mx, 2));
            mx = fmaxf(mx, __shfl_xor(mx, 4));
            float s = 0.f, pv = 0.f;
#pragma unroll
            for (int j = 0; j < 4; ++j) {
                const float e = __expf(acc[i][j] - mx);
                s += e;
                pv = fmaf(e, vvv[j], pv);
            }
            s += __shfl_xor(s, 1);  s += __shfl_xor(s, 2);  s += __shfl_xor(s, 4);
            pv += __shfl_xor(pv, 1); pv += __shfl_xor(pv, 2); pv += __shfl_xor(pv, 4);
            outv[i] = pv / s;
        }
        if (tj == 0) {
            float4 o4 = {outv[0], outv[1], outv[2], outv[3]};
            *(float4*)&qkv[rowbase + (size_t)p2 * D_ + cbase + ti * 4] = o4;
        }
    }
}

// ---------------- K4: proj 1x1 + BN + SiLU + residual, out (b,c,p) ----------
__global__ __launch_bounds__(256) void k_proj(
        const float* __restrict__ qkv, const float* __restrict__ pw,
        const float* __restrict__ pb, const float* __restrict__ gamma,
        const float* __restrict__ beta, const float* __restrict__ mean,
        const float* __restrict__ var, const float* __restrict__ x,
        float* __restrict__ out) {
    const int m0 = blockIdx.x * 128;
    const int o0 = blockIdx.y * 64;
    const int tid = threadIdx.x;
    const int tp = tid & 15;
    const int to = tid >> 4;
    __shared__ float Q_sh[16][132];
    __shared__ float W_sh[16][68];
    float acc[8][4] = {};
    for (int c0 = 0; c0 < D_; c0 += 16) {
        float4 a[2];
#pragma unroll
        for (int r = 0; r < 2; ++r) {
            const int lin4 = tid + r * 256;
            const int m_l = lin4 >> 2;
            const int c_l4 = (lin4 & 3) * 4;
            a[r] = *(const float4*)&qkv[(m0 + m_l) * D_ + c0 + c_l4];
        }
        const int o_l = tid >> 2;
        const int c_l4w = (tid & 3) * 4;
        const float4 wv = *(const float4*)&pw[(o0 + o_l) * D_ + c0 + c_l4w];
        __syncthreads();
#pragma unroll
        for (int r = 0; r < 2; ++r) {
            const int lin4 = tid + r * 256;
            const int m_l = lin4 >> 2;
            const int c_l4 = (lin4 & 3) * 4;
            Q_sh[c_l4 + 0][m_l] = a[r].x;
            Q_sh[c_l4 + 1][m_l] = a[r].y;
            Q_sh[c_l4 + 2][m_l] = a[r].z;
            Q_sh[c_l4 + 3][m_l] = a[r].w;
        }
        W_sh[c_l4w + 0][o_l] = wv.x;
        W_sh[c_l4w + 1][o_l] = wv.y;
        W_sh[c_l4w + 2][o_l] = wv.z;
        W_sh[c_l4w + 3][o_l] = wv.w;
        __syncthreads();
#pragma unroll
        for (int kk = 0; kk < 16; ++kk) {
            const float4 a0 = *(const float4*)&Q_sh[kk][tp * 4];
            const float4 a1 = *(const float4*)&Q_sh[kk][64 + tp * 4];
            const float4 w4 = *(const float4*)&W_sh[kk][to * 4];
            const float am[8] = {a0.x, a0.y, a0.z, a0.w, a1.x, a1.y, a1.z, a1.w};
            const float wm[4] = {w4.x, w4.y, w4.z, w4.w};
#pragma unroll
            for (int i = 0; i < 8; ++i)
#pragma unroll
                for (int j = 0; j < 4; ++j)
                    acc[i][j] = fmaf(am[i], wm[j], acc[i][j]);
        }
    }
    const int ob = o0 + to * 4;
    const float4 pb4 = *(const float4*)&pb[ob];
    const float4 gm4 = *(const float4*)&gamma[ob];
    const float4 bt4 = *(const float4*)&beta[ob];
    const float4 mn4 = *(const float4*)&mean[ob];
    const float4 vr4 = *(const float4*)&var[ob];
    const float pbv[4] = {pb4.x, pb4.y, pb4.z, pb4.w};
    const float mnv[4] = {mn4.x, mn4.y, mn4.z, mn4.w};
    const float btv[4] = {bt4.x, bt4.y, bt4.z, bt4.w};
    const float gmv[4] = {gm4.x, gm4.y, gm4.z, gm4.w};
    const float vrv[4] = {vr4.x, vr4.y, vr4.z, vr4.w};
    float invv[4];
#pragma unroll
    for (int j = 0; j < 4; ++j) invv[j] = gmv[j] * rsqrtf(vrv[j] + 1e-5f);
#pragma unroll
    for (int j = 0; j < 4; ++j) {
        const int oG = ob + j;
#pragma unroll
        for (int half = 0; half < 2; ++half) {
            const int m = m0 + half * 64 + tp * 4;   // 4 consecutive m, same b
            const int bb = m / HW_;
            const int p = m - bb * HW_;
            const int base = (bb * D_ + oG) * HW_ + p;
            const float4 ide = *(const float4*)&x[base];
            const float idev[4] = {ide.x, ide.y, ide.z, ide.w};
            float rr[4];
#pragma unroll
            for (int i = 0; i < 4; ++i) {
                const float val = acc[half * 4 + i][j] + pbv[j];
                const float xn = (val - mnv[j]) * invv[j] + btv[j];
                const float sg = 1.f / (1.f + __expf(-xn));
                rr[i] = xn * sg + idev[i];
            }
            float4 r4 = {rr[0], rr[1], rr[2], rr[3]};
            *(float4*)&out[base] = r4;
        }
    }
}

extern "C" void kernel_launch(void* const* d_in, const int* in_sizes, int n_in,
                              void* d_out, int out_size, void* d_ws, size_t ws_size,
                              hipStream_t stream) {
    const float* x   = (const float*)d_in[0];
    const float* qkw = (const float*)d_in[1];
    const float* qkb = (const float*)d_in[2];
    const float* vw  = (const float*)d_in[3];
    const float* vb  = (const float*)d_in[4];
    const float* pw  = (const float*)d_in[5];
    const float* pb  = (const float*)d_in[6];
    const float* gm  = (const float*)d_in[7];
    const float* bt  = (const float*)d_in[8];
    const float* mn  = (const float*)d_in[9];
    const float* vr  = (const float*)d_in[10];
    float* out = (float*)d_out;

    float* q   = (float*)d_ws;                    // (b,p,c) 25.7 MB
    float* kk  = q + (size_t)M_ * D_;             // (b,p,c)
    float* vv  = kk + (size_t)M_ * D_;            // (b,p,c)
    float* qkv = vv + (size_t)M_ * D_;            // (b,p,c)

    k_qkconv<<<dim3(8 * H_ * B_), dim3(64), 0, stream>>>(x, qkw, qkb, q, kk);
    k_vgemm<<<dim3(M_ / 128, 4), dim3(256), 0, stream>>>(x, vw, vb, vv);
    k_attn<<<dim3(HW_, B_), dim3(256), 0, stream>>>(q, kk, vv, qkv);
    k_proj<<<dim3(M_ / 128, 4), dim3(256), 0, stream>>>(qkv, pw, pb, gm, bt, mn, vr, x, out);
}

// Round 7
// 390.901 us; speedup vs baseline: 1.1067x; 1.0082x over previous
//
#include <hip/hip_runtime.h>
#include <math.h>

namespace {
constexpr int B_ = 8;
constexpr int D_ = 256;
constexpr int H_ = 56;
constexpr int W_ = 56;
constexpr int HW_ = H_ * W_;   // 3136
constexpr int M_ = B_ * HW_;   // 25088
constexpr float LOG2E = 1.44269504088896340736f;

typedef short bf16x8 __attribute__((ext_vector_type(8)));
typedef float f32x16 __attribute__((ext_vector_type(16)));

// bf16 round-to-nearest-even via bit math (no hip_bf16.h dependency).
__device__ inline unsigned short f2bf(float f) {
    unsigned int u = __float_as_uint(f);
    u += 0x7FFFu + ((u >> 16) & 1u);
    return (unsigned short)(u >> 16);
}
__device__ inline unsigned int pk2(float a, float b) {
    return (unsigned int)f2bf(a) | ((unsigned int)f2bf(b) << 16);
}
__device__ inline bf16x8 mkfrag(unsigned int a, unsigned int b,
                                unsigned int c, unsigned int d) {
    union { unsigned int u[4]; bf16x8 v; } x;
    x.u[0] = a; x.u[1] = b; x.u[2] = c; x.u[3] = d;
    return x.v;
}
// v_permlane32_swap_b32 D,S: D.hi-lanes <-> S.lo-lanes
__device__ inline void swapLH(unsigned int& a, unsigned int& b) {
    asm volatile("v_permlane32_swap_b32 %0, %1" : "+v"(a), "+v"(b));
}
}

// ---------------- K1: depthwise 3x3 qk conv -> q,k in (b,p,c) layout --------
// conv output channel oc uses input channel oc>>1 (XLA group rule).
// q-half (oc<256) is pre-scaled by log2(e) so attention softmax uses exp2.
__global__ __launch_bounds__(64) void k_qkconv(
        const float* __restrict__ x, const float* __restrict__ qkw,
        const float* __restrict__ qkb,
        float* __restrict__ q, float* __restrict__ k) {
    const int bid = blockIdx.x;
    const int g = bid & 7;                 // 8 groups of 64 out-channels
    const int y = (bid >> 3) % H_;
    const int b = bid / (8 * H_);
    const int tid = threadIdx.x;           // 0..63
    const int oc = g * 64 + tid;           // 0..511
    const int cin0 = g * 32;
    __shared__ float xs[32][3][58];
    for (int lin = tid; lin < 32 * 3 * 58; lin += 64) {
        const int ci = lin / 174;
        const int r = (lin / 58) % 3;
        const int col = lin % 58;
        const int yy = y - 1 + r;
        const int xx = col - 1;
        float v = 0.f;
        if ((unsigned)yy < (unsigned)H_ && (unsigned)xx < (unsigned)W_)
            v = x[((b * D_ + cin0 + ci) * H_ + yy) * W_ + xx];
        xs[ci][r][col] = v;
    }
    __syncthreads();
    float w[9];
#pragma unroll
    for (int t = 0; t < 9; ++t) w[t] = qkw[oc * 9 + t];
    float bias = qkb[oc];
    if (oc < 256) {                        // q-half: fold log2e
#pragma unroll
        for (int t = 0; t < 9; ++t) w[t] *= LOG2E;
        bias *= LOG2E;
    }
    const int cl = tid >> 1;               // local cin
    float* const dst = (oc < 256) ? q : k;
    const int od = oc & 255;
    for (int xx = 0; xx < W_; ++xx) {
        float acc = bias;
#pragma unroll
        for (int t = 0; t < 9; ++t)
            acc = fmaf(w[t], xs[cl][t / 3][xx + (t % 3)], acc);
        dst[(b * HW_ + y * W_ + xx) * D_ + od] = acc;
    }
}

// ---------------- K2: v = 1x1 conv, out layout (b,p,c) ----------------------
__global__ __launch_bounds__(256) void k_vgemm(
        const float* __restrict__ x, const float* __restrict__ vw,
        const float* __restrict__ vb, float* __restrict__ vv) {
    const int m0 = blockIdx.x * 128;
    const int o0 = blockIdx.y * 64;
    const int tid = threadIdx.x;
    const int tp = tid & 15;
    const int to = tid >> 4;               // 0..15
    __shared__ float A_sh[16][132];
    __shared__ float W_sh[16][68];
    float acc[8][4] = {};
    for (int c0 = 0; c0 < D_; c0 += 16) {
        float4 a[2];
#pragma unroll
        for (int r = 0; r < 2; ++r) {
            const int lin4 = tid + r * 256;
            const int c_l = lin4 >> 5;
            const int m_l = (lin4 & 31) * 4;
            const int m = m0 + m_l;
            const int bb = m / HW_;
            const int p = m - bb * HW_;
            a[r] = *(const float4*)&x[(bb * D_ + c0 + c_l) * HW_ + p];
        }
        const int o_l = tid >> 2;
        const int c_l4 = (tid & 3) * 4;
        const float4 wv = *(const float4*)&vw[(o0 + o_l) * D_ + c0 + c_l4];
        __syncthreads();
#pragma unroll
        for (int r = 0; r < 2; ++r) {
            const int lin4 = tid + r * 256;
            const int c_l = lin4 >> 5;
            const int m_l = (lin4 & 31) * 4;
            *(float4*)&A_sh[c_l][m_l] = a[r];
        }
        W_sh[c_l4 + 0][o_l] = wv.x;
        W_sh[c_l4 + 1][o_l] = wv.y;
        W_sh[c_l4 + 2][o_l] = wv.z;
        W_sh[c_l4 + 3][o_l] = wv.w;
        __syncthreads();
#pragma unroll
        for (int kk = 0; kk < 16; ++kk) {
            const float4 a0 = *(const float4*)&A_sh[kk][tp * 4];
            const float4 a1 = *(const float4*)&A_sh[kk][64 + tp * 4];
            const float4 w4 = *(const float4*)&W_sh[kk][to * 4];
            const float am[8] = {a0.x, a0.y, a0.z, a0.w, a1.x, a1.y, a1.z, a1.w};
            const float wm[4] = {w4.x, w4.y, w4.z, w4.w};
#pragma unroll
            for (int i = 0; i < 8; ++i)
#pragma unroll
                for (int j = 0; j < 4; ++j)
                    acc[i][j] = fmaf(am[i], wm[j], acc[i][j]);
        }
    }
    const float4 vb4 = *(const float4*)&vb[o0 + to * 4];
    const float bv[4] = {vb4.x, vb4.y, vb4.z, vb4.w};
#pragma unroll
    for (int i = 0; i < 8; ++i) {
        const int m_l = (i < 4) ? (tp * 4 + i) : (64 + tp * 4 + i - 4);
        const int m = m0 + m_l;
        float4 o4;
        o4.x = acc[i][0] + bv[0];
        o4.y = acc[i][1] + bv[1];
        o4.z = acc[i][2] + bv[2];
        o4.w = acc[i][3] + bv[3];
        *(float4*)&vv[m * D_ + o0 + to * 4] = o4;
    }
}

// ---------------- K3: per-pixel 32x32 channel attention via MFMA ------------
// Block = (b,p2), 4 waves x 2 heads. S' = mfma(K,Q) so S'[k_ch][q_ch];
// softmax over D-rows; exp2 (log2e folded into q); P->bf16 + permlane32_swap
// to B-layout; PV + denominator via augmented-A (row0=v, row1=ones) MFMA.
__global__ __launch_bounds__(256) void k_attn(
        const float* __restrict__ q, const float* __restrict__ kko,
        const float* __restrict__ v, float* __restrict__ qkv) {
    const int p2 = blockIdx.x;
    const int b = blockIdx.y;
    const int tid = threadIdx.x;
    __shared__ __align__(16) unsigned short qlds[2][256][8];
    __shared__ __align__(16) unsigned short klds[2][256][8];
    __shared__ float vs[256];
    const size_t rowbase = (size_t)(b * HW_) * D_;

    float qt[9], kt[9];
#pragma unroll
    for (int k2 = 0; k2 < 9; ++k2) {
        const int t = p2 * 9 + k2;         // all block-uniform (SALU)
        const int kp = t / HW_;
        const int pp = t - kp * HW_;
        const int yy = pp / W_;
        const int xx = pp - yy * W_;
        const int sy = yy + kp / 3 - 1;
        const int sx = xx + kp % 3 - 1;
        float qv = 0.f, kv = 0.f;
        if ((unsigned)sy < (unsigned)H_ && (unsigned)sx < (unsigned)W_) {
            const size_t off = rowbase + (size_t)(sy * W_ + sx) * D_ + tid;
            qv = q[off];
            kv = kko[off];
        }
        qt[k2] = qv;
        kt[k2] = kv;
    }
    vs[tid] = v[rowbase + (size_t)p2 * D_ + tid];
    unsigned short qb[16], kb[16];
#pragma unroll
    for (int i = 0; i < 16; ++i) {
        qb[i] = (i < 9) ? f2bf(qt[i]) : (unsigned short)0;
        kb[i] = (i < 9) ? f2bf(kt[i]) : (unsigned short)0;
    }
    *(uint4*)&qlds[0][tid][0] = *(const uint4*)&qb[0];
    *(uint4*)&qlds[1][tid][0] = *(const uint4*)&qb[8];
    *(uint4*)&klds[0][tid][0] = *(const uint4*)&kb[0];
    *(uint4*)&klds[1][tid][0] = *(const uint4*)&kb[8];
    __syncthreads();

    const int wid = tid >> 6;
    const int lane = tid & 63;
    const int lm = lane & 31;
    const int g = lane >> 5;               // tap-group / k-group

    f32x16 zero;
#pragma unroll
    for (int r = 0; r < 16; ++r) zero[r] = 0.f;

#pragma unroll
    for (int hh = 0; hh < 2; ++hh) {
        const int cbase = (wid + hh * 4) * 32;
        const bf16x8 af = *(const bf16x8*)&klds[g][cbase + lm][0];  // A: K
        const bf16x8 bfq = *(const bf16x8*)&qlds[g][cbase + lm][0]; // B: Q
        f32x16 s = __builtin_amdgcn_mfma_f32_32x32x16_bf16(af, bfq, zero, 0, 0, 0);
        float p[16];
#pragma unroll
        for (int r = 0; r < 16; ++r) p[r] = exp2f(s[r]);
        unsigned int X[8];
#pragma unroll
        for (int w = 0; w < 8; ++w) X[w] = pk2(p[2 * w], p[2 * w + 1]);
        // D-layout -> B-layout half-exchange
        swapLH(X[0], X[2]);  swapLH(X[1], X[3]);
        swapLH(X[4], X[6]);  swapLH(X[5], X[7]);
        const bf16x8 b2c0 = mkfrag(X[0], X[1], X[2], X[3]);   // rows 0..15
        const bf16x8 b2c1 = mkfrag(X[4], X[5], X[6], X[7]);   // rows 16..31
        // A2: row0 = v, row1 = ones, rest 0
        unsigned int aw0[4], aw1[4];
#pragma unroll
        for (int w = 0; w < 4; ++w) {
            unsigned int v0 = 0, v1 = 0;
            if (lm == 0) {
                const int i0 = cbase + 8 * g + 2 * w;
                v0 = pk2(vs[i0], vs[i0 + 1]);
                v1 = pk2(vs[i0 + 16], vs[i0 + 17]);
            } else if (lm == 1) {
                v0 = 0x3F803F80u;          // bf16(1.0) x2
                v1 = 0x3F803F80u;
            }
            aw0[w] = v0;
            aw1[w] = v1;
        }
        const bf16x8 a2c0 = mkfrag(aw0[0], aw0[1], aw0[2], aw0[3]);
        const bf16x8 a2c1 = mkfrag(aw1[0], aw1[1], aw1[2], aw1[3]);
        f32x16 acc = __builtin_amdgcn_mfma_f32_32x32x16_bf16(a2c0, b2c0, zero, 0, 0, 0);
        acc = __builtin_amdgcn_mfma_f32_32x32x16_bf16(a2c1, b2c1, acc, 0, 0, 0);
        if (lane < 32)                     // reg0 = numerator, reg1 = denominator
            qkv[rowbase + (size_t)p2 * D_ + cbase + lane] = acc[0] / acc[1];
    }
}

// ---------------- K4: proj 1x1 + BN + SiLU + residual, out (b,c,p) ----------
__global__ __launch_bounds__(256) void k_proj(
        const float* __restrict__ qkv, const float* __restrict__ pw,
        const float* __restrict__ pb, const float* __restrict__ gamma,
        const float* __restrict__ beta, const float* __restrict__ mean,
        const float* __restrict__ var, const float* __restrict__ x,
        float* __restrict__ out) {
    const int m0 = blockIdx.x * 128;
    const int o0 = blockIdx.y * 64;
    const int tid = threadIdx.x;
    const int tp = tid & 15;
    const int to = tid >> 4;
    __shared__ float Q_sh[16][132];
    __shared__ float W_sh[16][68];
    float acc[8][4] = {};
    for (int c0 = 0; c0 < D_; c0 += 16) {
        float4 a[2];
#pragma unroll
        for (int r = 0; r < 2; ++r) {
            const int lin4 = tid + r * 256;
            const int m_l = lin4 >> 2;
            const int c_l4 = (lin4 & 3) * 4;
            a[r] = *(const float4*)&qkv[(m0 + m_l) * D_ + c0 + c_l4];
        }
        const int o_l = tid >> 2;
        const int c_l4w = (tid & 3) * 4;
        const float4 wv = *(const float4*)&pw[(o0 + o_l) * D_ + c0 + c_l4w];
        __syncthreads();
#pragma unroll
        for (int r = 0; r < 2; ++r) {
            const int lin4 = tid + r * 256;
            const int m_l = lin4 >> 2;
            const int c_l4 = (lin4 & 3) * 4;
            Q_sh[c_l4 + 0][m_l] = a[r].x;
            Q_sh[c_l4 + 1][m_l] = a[r].y;
            Q_sh[c_l4 + 2][m_l] = a[r].z;
            Q_sh[c_l4 + 3][m_l] = a[r].w;
        }
        W_sh[c_l4w + 0][o_l] = wv.x;
        W_sh[c_l4w + 1][o_l] = wv.y;
        W_sh[c_l4w + 2][o_l] = wv.z;
        W_sh[c_l4w + 3][o_l] = wv.w;
        __syncthreads();
#pragma unroll
        for (int kk = 0; kk < 16; ++kk) {
            const float4 a0 = *(const float4*)&Q_sh[kk][tp * 4];
            const float4 a1 = *(const float4*)&Q_sh[kk][64 + tp * 4];
            const float4 w4 = *(const float4*)&W_sh[kk][to * 4];
            const float am[8] = {a0.x, a0.y, a0.z, a0.w, a1.x, a1.y, a1.z, a1.w};
            const float wm[4] = {w4.x, w4.y, w4.z, w4.w};
#pragma unroll
            for (int i = 0; i < 8; ++i)
#pragma unroll
                for (int j = 0; j < 4; ++j)
                    acc[i][j] = fmaf(am[i], wm[j], acc[i][j]);
        }
    }
    const int ob = o0 + to * 4;
    const float4 pb4 = *(const float4*)&pb[ob];
    const float4 gm4 = *(const float4*)&gamma[ob];
    const float4 bt4 = *(const float4*)&beta[ob];
    const float4 mn4 = *(const float4*)&mean[ob];
    const float4 vr4 = *(const float4*)&var[ob];
    const float pbv[4] = {pb4.x, pb4.y, pb4.z, pb4.w};
    const float mnv[4] = {mn4.x, mn4.y, mn4.z, mn4.w};
    const float btv[4] = {bt4.x, bt4.y, bt4.z, bt4.w};
    const float gmv[4] = {gm4.x, gm4.y, gm4.z, gm4.w};
    const float vrv[4] = {vr4.x, vr4.y, vr4.z, vr4.w};
    float invv[4];
#pragma unroll
    for (int j = 0; j < 4; ++j) invv[j] = gmv[j] * rsqrtf(vrv[j] + 1e-5f);
#pragma unroll
    for (int j = 0; j < 4; ++j) {
        const int oG = ob + j;
#pragma unroll
        for (int half = 0; half < 2; ++half) {
            const int m = m0 + half * 64 + tp * 4;   // 4 consecutive m, same b
            const int bb = m / HW_;
            const int p = m - bb * HW_;
            const int base = (bb * D_ + oG) * HW_ + p;
            const float4 ide = *(const float4*)&x[base];
            const float idev[4] = {ide.x, ide.y, ide.z, ide.w};
            float rr[4];
#pragma unroll
            for (int i = 0; i < 4; ++i) {
                const float val = acc[half * 4 + i][j] + pbv[j];
                const float xn = (val - mnv[j]) * invv[j] + btv[j];
                const float sg = 1.f / (1.f + __expf(-xn));
                rr[i] = xn * sg + idev[i];
            }
            float4 r4 = {rr[0], rr[1], rr[2], rr[3]};
            *(float4*)&out[base] = r4;
        }
    }
}

extern "C" void kernel_launch(void* const* d_in, const int* in_sizes, int n_in,
                              void* d_out, int out_size, void* d_ws, size_t ws_size,
                              hipStream_t stream) {
    const float* x   = (const float*)d_in[0];
    const float* qkw = (const float*)d_in[1];
    const float* qkb = (const float*)d_in[2];
    const float* vw  = (const float*)d_in[3];
    const float* vb  = (const float*)d_in[4];
    const float* pw  = (const float*)d_in[5];
    const float* pb  = (const float*)d_in[6];
    const float* gm  = (const float*)d_in[7];
    const float* bt  = (const float*)d_in[8];
    const float* mn  = (const float*)d_in[9];
    const float* vr  = (const float*)d_in[10];
    float* out = (float*)d_out;

    float* q   = (float*)d_ws;                    // (b,p,c) 25.7 MB
    float* kk  = q + (size_t)M_ * D_;             // (b,p,c)
    float* vv  = kk + (size_t)M_ * D_;            // (b,p,c)
    float* qkv = vv + (size_t)M_ * D_;            // (b,p,c)

    k_qkconv<<<dim3(8 * H_ * B_), dim3(64), 0, stream>>>(x, qkw, qkb, q, kk);
    k_vgemm<<<dim3(M_ / 128, 4), dim3(256), 0, stream>>>(x, vw, vb, vv);
    k_attn<<<dim3(HW_, B_), dim3(256), 0, stream>>>(q, kk, vv, qkv);
    k_proj<<<dim3(M_ / 128, 4), dim3(256), 0, stream>>>(qkv, pw, pb, gm, bt, mn, vr, x, out);
}

// Round 9
// 273.023 us; speedup vs baseline: 1.5846x; 1.4318x over previous
//
#include <hip/hip_runtime.h>
#include <math.h>

namespace {
constexpr int B_ = 8;
constexpr int D_ = 256;
constexpr int H_ = 56;
constexpr int W_ = 56;
constexpr int HW_ = H_ * W_;   // 3136
constexpr int M_ = B_ * HW_;   // 25088
constexpr float LOG2E = 1.44269504088896340736f;
typedef unsigned short u16;
typedef short bf16x8 __attribute__((ext_vector_type(8)));
typedef float f32x16 __attribute__((ext_vector_type(16)));

// bf16 RNE via bit math
__device__ inline u16 f2bf(float f) {
    unsigned int u = __float_as_uint(f);
    u += 0x7FFFu + ((u >> 16) & 1u);
    return (u16)(u >> 16);
}
// packed f32x2 -> bf16x2 in one instruction (low = a, high = b)
__device__ inline unsigned int pk2a(float a, float b) {
    unsigned int r;
    asm("v_cvt_pk_bf16_f32 %0, %1, %2" : "=v"(r) : "v"(a), "v"(b));
    return r;
}
__device__ inline bf16x8 mkfrag(unsigned int a, unsigned int b,
                                unsigned int c, unsigned int d) {
    union { unsigned int u[4]; bf16x8 v; } x;
    x.u[0] = a; x.u[1] = b; x.u[2] = c; x.u[3] = d;
    return x.v;
}
__device__ inline void swapLH(unsigned int& a, unsigned int& b) {
    asm volatile("v_permlane32_swap_b32 %0, %1" : "+v"(a), "+v"(b));
}
}

// ---------------- K0a: weight prep: vw->bf16 ; pw*bnscale->bf16 ; fused bias
__global__ __launch_bounds__(256) void k_wprep(
        const float* __restrict__ vw, const float* __restrict__ pw,
        const float* __restrict__ pb, const float* __restrict__ gm,
        const float* __restrict__ bt, const float* __restrict__ mn,
        const float* __restrict__ vr,
        u16* __restrict__ vwb, u16* __restrict__ pwb, float* __restrict__ pbias) {
    const int o = blockIdx.x;
    const int c = threadIdx.x;
    const float inv = gm[o] * rsqrtf(vr[o] + 1e-5f);
    vwb[o * 256 + c] = f2bf(vw[o * 256 + c]);
    pwb[o * 256 + c] = f2bf(pw[o * 256 + c] * inv);
    if (c == 0) pbias[o] = (pb[o] - mn[o]) * inv + bt[o];
}

// ---------------- K0b: x (b,c,p) f32 -> xb (b,p,c) bf16 --------------------
__global__ __launch_bounds__(256) void k_xpose(
        const float* __restrict__ x, u16* __restrict__ xb) {
    const int p0 = blockIdx.x * 32;
    const int c0 = blockIdx.y * 32;
    const int b = blockIdx.z;
    __shared__ float tile[32][36];
    const int t = threadIdx.x;
    {
        const int cl = t >> 3;
        const int pl4 = (t & 7) * 4;
        const float4 v4 = *(const float4*)&x[((size_t)(b * 256 + c0 + cl)) * HW_ + p0 + pl4];
        *(float4*)&tile[cl][pl4] = v4;
    }
    __syncthreads();
    const int pl = t >> 3;
    const int cl4 = (t & 7) * 4;
    uint2 o;
    o.x = pk2a(tile[cl4 + 0][pl], tile[cl4 + 1][pl]);
    o.y = pk2a(tile[cl4 + 2][pl], tile[cl4 + 3][pl]);
    *(uint2*)&xb[((size_t)(b * HW_ + p0 + pl)) * 256 + c0 + cl4] = o;
}

// ---------------- K1: depthwise 3x3 qk conv -> q,k (b,p,c) bf16 -------------
// out channel oc uses input channel oc>>1; q-half pre-scaled by log2(e).
__global__ __launch_bounds__(64) void k_qkconv(
        const float* __restrict__ x, const float* __restrict__ qkw,
        const float* __restrict__ qkb,
        u16* __restrict__ q, u16* __restrict__ k) {
    const int bid = blockIdx.x;
    const int g = bid & 7;
    const int y = (bid >> 3) % H_;
    const int b = bid / (8 * H_);
    const int tid = threadIdx.x;
    const int oc = g * 64 + tid;
    const int cin0 = g * 32;
    __shared__ float xs[32][3][58];
    for (int lin = tid; lin < 32 * 3 * 58; lin += 64) {
        const int ci = lin / 174;
        const int r = (lin / 58) % 3;
        const int col = lin % 58;
        const int yy = y - 1 + r;
        const int xx = col - 1;
        float v = 0.f;
        if ((unsigned)yy < (unsigned)H_ && (unsigned)xx < (unsigned)W_)
            v = x[((b * D_ + cin0 + ci) * H_ + yy) * W_ + xx];
        xs[ci][r][col] = v;
    }
    __syncthreads();
    float w[9];
#pragma unroll
    for (int t = 0; t < 9; ++t) w[t] = qkw[oc * 9 + t];
    float bias = qkb[oc];
    if (oc < 256) {
#pragma unroll
        for (int t = 0; t < 9; ++t) w[t] *= LOG2E;
        bias *= LOG2E;
    }
    const int cl = tid >> 1;
    u16* const dst = (oc < 256) ? q : k;
    const int od = oc & 255;
    for (int xx = 0; xx < W_; ++xx) {
        float acc = bias;
#pragma unroll
        for (int t = 0; t < 9; ++t)
            acc = fmaf(w[t], xs[cl][t / 3][xx + (t % 3)], acc);
        dst[(size_t)(b * HW_ + y * W_ + xx) * D_ + od] = f2bf(acc);
    }
}

// ---------------- K2: v = xb * vwb^T + vb -> vvb (b,p,c) bf16, MFMA ---------
__global__ __launch_bounds__(256) void k_vgemm(
        const u16* __restrict__ xb, const u16* __restrict__ vwb,
        const float* __restrict__ vb, u16* __restrict__ vvb) {
    const int m0 = blockIdx.x * 64;
    const int n0 = blockIdx.y * 64;
    const int t = threadIdx.x;
    __shared__ __align__(16) u16 A_lds[2048];   // [mh][s][g][32][8]
    __shared__ __align__(16) u16 B_lds[2048];   // [nh][s][g][32][8]
    const int kc = t >> 6, r = t & 63;
    const size_t a_src = ((size_t)m0 + r) * 256 + 8 * kc;
    const size_t b_src = ((size_t)(n0 + r)) * 256 + 8 * kc;
    const int dst = (r >> 5) * 1024 + (kc >> 1) * 512 + (kc & 1) * 256 + (r & 31) * 8;
    const int l = t & 63, w = t >> 6;
    const int mh = w >> 1, nh = w & 1;
    const int fo = (l >> 5) * 256 + (l & 31) * 8;
    f32x16 acc;
#pragma unroll
    for (int i = 0; i < 16; ++i) acc[i] = 0.f;
    for (int kt = 0; kt < 8; ++kt) {
        const uint4 av = *(const uint4*)&xb[a_src + kt * 32];
        const uint4 bv = *(const uint4*)&vwb[b_src + kt * 32];
        __syncthreads();
        *(uint4*)&A_lds[dst] = av;
        *(uint4*)&B_lds[dst] = bv;
        __syncthreads();
        const bf16x8 a0 = *(const bf16x8*)&A_lds[mh * 1024 + fo];
        const bf16x8 b0 = *(const bf16x8*)&B_lds[nh * 1024 + fo];
        acc = __builtin_amdgcn_mfma_f32_32x32x16_bf16(a0, b0, acc, 0, 0, 0);
        const bf16x8 a1 = *(const bf16x8*)&A_lds[mh * 1024 + 512 + fo];
        const bf16x8 b1 = *(const bf16x8*)&B_lds[nh * 1024 + 512 + fo];
        acc = __builtin_amdgcn_mfma_f32_32x32x16_bf16(a1, b1, acc, 0, 0, 0);
    }
    const int n = n0 + nh * 32 + (l & 31);
    const float bias = vb[n];
    const int g = l >> 5;
    const size_t obase = ((size_t)(m0 + mh * 32)) * 256 + n;
#pragma unroll
    for (int rr = 0; rr < 16; ++rr) {
        const int mrow = (rr & 3) + 8 * (rr >> 2) + 4 * g;
        vvb[obase + (size_t)mrow * 256] = f2bf(acc[rr] + bias);
    }
}

// ---------------- K3: per-pixel 32x32 channel attention (bf16 in/out) -------
__global__ __launch_bounds__(256) void k_attn(
        const u16* __restrict__ qb_g, const u16* __restrict__ kb_g,
        const u16* __restrict__ vvb, u16* __restrict__ qkvb) {
    const int p2 = blockIdx.x;
    const int b = blockIdx.y;
    const int tid = threadIdx.x;
    __shared__ __align__(16) u16 qlds[2][256][8];
    __shared__ __align__(16) u16 klds[2][256][8];
    __shared__ unsigned int vs_u[128];
    const size_t rowbase = (size_t)(b * HW_) * D_;

    union { u16 s[16]; uint4 q[2]; } qu, ku;
#pragma unroll
    for (int k2 = 0; k2 < 9; ++k2) {
        const int tt = p2 * 9 + k2;        // block-uniform
        const int kp = tt / HW_;
        const int pp = tt - kp * HW_;
        const int yy = pp / W_;
        const int xx = pp - yy * W_;
        const int sy = yy + kp / 3 - 1;
        const int sx = xx + kp % 3 - 1;
        u16 a = 0, c = 0;
        if ((unsigned)sy < (unsigned)H_ && (unsigned)sx < (unsigned)W_) {
            const size_t off = rowbase + (size_t)(sy * W_ + sx) * D_ + tid;
            a = qb_g[off];
            c = kb_g[off];
        }
        qu.s[k2] = a;
        ku.s[k2] = c;
    }
#pragma unroll
    for (int i = 9; i < 16; ++i) { qu.s[i] = 0; ku.s[i] = 0; }
    if (tid < 128)
        vs_u[tid] = *(const unsigned int*)&vvb[rowbase + (size_t)p2 * D_ + 2 * tid];
    *(uint4*)&qlds[0][tid][0] = qu.q[0];
    *(uint4*)&qlds[1][tid][0] = qu.q[1];
    *(uint4*)&klds[0][tid][0] = ku.q[0];
    *(uint4*)&klds[1][tid][0] = ku.q[1];
    __syncthreads();

    const int wid = tid >> 6;
    const int lane = tid & 63;
    const int lm = lane & 31;
    const int g = lane >> 5;

    f32x16 zero;
#pragma unroll
    for (int r = 0; r < 16; ++r) zero[r] = 0.f;

#pragma unroll
    for (int hh = 0; hh < 2; ++hh) {
        const int cbase = (wid + hh * 4) * 32;
        const bf16x8 af = *(const bf16x8*)&klds[g][cbase + lm][0];  // A: K
        const bf16x8 bfq = *(const bf16x8*)&qlds[g][cbase + lm][0]; // B: Q
        f32x16 s = __builtin_amdgcn_mfma_f32_32x32x16_bf16(af, bfq, zero, 0, 0, 0);
        float p[16];
#pragma unroll
        for (int r = 0; r < 16; ++r) p[r] = __builtin_amdgcn_exp2f(s[r]);
        unsigned int X[8];
#pragma unroll
        for (int w = 0; w < 8; ++w) X[w] = pk2a(p[2 * w], p[2 * w + 1]);
        swapLH(X[0], X[2]);  swapLH(X[1], X[3]);
        swapLH(X[4], X[6]);  swapLH(X[5], X[7]);
        const bf16x8 b2c0 = mkfrag(X[0], X[1], X[2], X[3]);
        const bf16x8 b2c1 = mkfrag(X[4], X[5], X[6], X[7]);
        // A2: row0 = v, row1 = ones
        unsigned int aw0[4], aw1[4];
#pragma unroll
        for (int w = 0; w < 4; ++w) {
            unsigned int v0 = 0, v1 = 0;
            if (lm == 0) {
                const int i0 = cbase / 2 + 4 * g + w;
                v0 = vs_u[i0];
                v1 = vs_u[i0 + 8];
            } else if (lm == 1) {
                v0 = 0x3F803F80u;
                v1 = 0x3F803F80u;
            }
            aw0[w] = v0;
            aw1[w] = v1;
        }
        const bf16x8 a2c0 = mkfrag(aw0[0], aw0[1], aw0[2], aw0[3]);
        const bf16x8 a2c1 = mkfrag(aw1[0], aw1[1], aw1[2], aw1[3]);
        f32x16 acc = __builtin_amdgcn_mfma_f32_32x32x16_bf16(a2c0, b2c0, zero, 0, 0, 0);
        acc = __builtin_amdgcn_mfma_f32_32x32x16_bf16(a2c1, b2c1, acc, 0, 0, 0);
        if (lane < 32)
            qkvb[rowbase + (size_t)p2 * D_ + cbase + lane] = f2bf(acc[0] / acc[1]);
    }
}

// ---------------- K4: proj MFMA + SiLU + residual, out (b,c,p) f32 ----------
__global__ __launch_bounds__(256) void k_proj(
        const u16* __restrict__ qkvb, const u16* __restrict__ pwb,
        const float* __restrict__ pbias, const float* __restrict__ x,
        float* __restrict__ out) {
    const int m0 = blockIdx.x * 64;
    const int n0 = blockIdx.y * 64;
    const int t = threadIdx.x;
    __shared__ __align__(16) u16 A_lds[2048];
    __shared__ __align__(16) u16 B_lds[2048];
    const int bb = m0 / HW_;
    const int p0 = m0 - bb * HW_;
    const int kc = t >> 6, r = t & 63;
    const size_t a_src = ((size_t)m0 + r) * 256 + 8 * kc;
    const size_t b_src = ((size_t)(n0 + r)) * 256 + 8 * kc;
    const int dst = (r >> 5) * 1024 + (kc >> 1) * 512 + (kc & 1) * 256 + (r & 31) * 8;
    const int l = t & 63, w = t >> 6;
    const int mh = w >> 1, nh = w & 1;
    const int fo = (l >> 5) * 256 + (l & 31) * 8;
    f32x16 acc;
#pragma unroll
    for (int i = 0; i < 16; ++i) acc[i] = 0.f;
    for (int kt = 0; kt < 8; ++kt) {
        const uint4 av = *(const uint4*)&qkvb[a_src + kt * 32];
        const uint4 bv = *(const uint4*)&pwb[b_src + kt * 32];
        __syncthreads();
        *(uint4*)&A_lds[dst] = av;
        *(uint4*)&B_lds[dst] = bv;
        __syncthreads();
        const bf16x8 a0 = *(const bf16x8*)&A_lds[mh * 1024 + fo];
        const bf16x8 b0 = *(const bf16x8*)&B_lds[nh * 1024 + fo];
        acc = __builtin_amdgcn_mfma_f32_32x32x16_bf16(a0, b0, acc, 0, 0, 0);
        const bf16x8 a1 = *(const bf16x8*)&A_lds[mh * 1024 + 512 + fo];
        const bf16x8 b1 = *(const bf16x8*)&B_lds[nh * 1024 + 512 + fo];
        acc = __builtin_amdgcn_mfma_f32_32x32x16_bf16(a1, b1, acc, 0, 0, 0);
    }
    const int n = n0 + nh * 32 + (l & 31);
    const float bias = pbias[n];
    const int g = l >> 5;
    const int prow = p0 + mh * 32;
    const float* xr = &x[((size_t)(bb * 256 + n)) * HW_ + prow];
    float* orow = &out[((size_t)(bb * 256 + n)) * HW_ + prow];
#pragma unroll
    for (int qd = 0; qd < 4; ++qd) {
        const int pofs = 8 * qd + 4 * g;
        const float4 ide = *(const float4*)&xr[pofs];
        const float idev[4] = {ide.x, ide.y, ide.z, ide.w};
        float rr[4];
#pragma unroll
        for (int i = 0; i < 4; ++i) {
            const float val = acc[qd * 4 + i] + bias;
            const float sg = 1.f / (1.f + __expf(-val));
            rr[i] = val * sg + idev[i];
        }
        float4 r4 = {rr[0], rr[1], rr[2], rr[3]};
        *(float4*)&orow[pofs] = r4;
    }
}

extern "C" void kernel_launch(void* const* d_in, const int* in_sizes, int n_in,
                              void* d_out, int out_size, void* d_ws, size_t ws_size,
                              hipStream_t stream) {
    const float* x   = (const float*)d_in[0];
    const float* qkw = (const float*)d_in[1];
    const float* qkb = (const float*)d_in[2];
    const float* vw  = (const float*)d_in[3];
    const float* vb  = (const float*)d_in[4];
    const float* pw  = (const float*)d_in[5];
    const float* pb  = (const float*)d_in[6];
    const float* gm  = (const float*)d_in[7];
    const float* bt  = (const float*)d_in[8];
    const float* mn  = (const float*)d_in[9];
    const float* vr  = (const float*)d_in[10];
    float* out = (float*)d_out;

    const size_t SZ = (size_t)M_ * D_;            // 6,422,528 elems
    u16* xb    = (u16*)d_ws;
    u16* qbuf  = xb + SZ;
    u16* kbuf  = qbuf + SZ;
    u16* vvb   = kbuf + SZ;
    u16* qkvb  = vvb + SZ;
    u16* vwb   = qkvb + SZ;
    u16* pwb   = vwb + 65536;
    float* pbias = (float*)(pwb + 65536);

    k_wprep<<<dim3(256), dim3(256), 0, stream>>>(vw, pw, pb, gm, bt, mn, vr, vwb, pwb, pbias);
    k_xpose<<<dim3(98, 8, 8), dim3(256), 0, stream>>>(x, xb);
    k_qkconv<<<dim3(8 * H_ * B_), dim3(64), 0, stream>>>(x, qkw, qkb, qbuf, kbuf);
    k_vgemm<<<dim3(392, 4), dim3(256), 0, stream>>>(xb, vwb, vb, vvb);
    k_attn<<<dim3(HW_, B_), dim3(256), 0, stream>>>(qbuf, kbuf, vvb, qkvb);
    k_proj<<<dim3(392, 4), dim3(256), 0, stream>>>(qkvb, pwb, pbias, x, out);
}